// Round 3
// baseline (104.463 us; speedup 1.0000x reference)
//
#include <hip/hip_runtime.h>
#include <hip/hip_bf16.h>

// MoE token scatter: out[dest[t], :] = token_hidden[t, :] where
// dest[t] = expert_offsets[expert_idx[t]] + slot_idx[t].
// HIDDEN = 1024 fp32 = 256 float4 per row. Pure memory-bound row permute:
// 268 MB read + 268 MB write, roofline ~85 us at 6.3 TB/s copy ceiling.
//
// Grid-stride over rows with 2048 blocks (8 per CU) so each block amortizes
// the dependent index-load chain over ~32 rows; nontemporal load/store since
// data streams once (537 MB >> 256 MB L3, caching is pure overhead).
//
// NOTE: __builtin_nontemporal_* requires a clang native vector type, not
// HIP_vector_type<float,4> (struct) — use ext_vector_type(4).

#define HIDDEN 1024
#define VEC 4                    // floats per thread
#define THREADS (HIDDEN / VEC)   // 256
#define GRID 2048                // 8 blocks/CU * 256 CUs

typedef float f32x4 __attribute__((ext_vector_type(4)));

__global__ __launch_bounds__(THREADS) void moe_scatter_kernel(
    const float* __restrict__ token_hidden,
    const int* __restrict__ expert_idx,
    const int* __restrict__ slot_idx,
    const int* __restrict__ expert_offsets,
    float* __restrict__ out,
    int num_tokens) {
    for (int t = blockIdx.x; t < num_tokens; t += gridDim.x) {
        const int e    = expert_idx[t];
        const int dest = expert_offsets[e] + slot_idx[t];

        const f32x4* __restrict__ src =
            reinterpret_cast<const f32x4*>(token_hidden + (size_t)t * HIDDEN);
        f32x4* __restrict__ dst =
            reinterpret_cast<f32x4*>(out + (size_t)dest * HIDDEN);

        f32x4 v = __builtin_nontemporal_load(&src[threadIdx.x]);
        __builtin_nontemporal_store(v, &dst[threadIdx.x]);
    }
}

extern "C" void kernel_launch(void* const* d_in, const int* in_sizes, int n_in,
                              void* d_out, int out_size, void* d_ws, size_t ws_size,
                              hipStream_t stream) {
    const float* token_hidden   = (const float*)d_in[0];
    const int*   expert_idx     = (const int*)d_in[1];
    const int*   slot_idx       = (const int*)d_in[2];
    const int*   expert_offsets = (const int*)d_in[3];
    float* out = (float*)d_out;

    const int num_tokens = in_sizes[1];  // expert_idx has one entry per token

    const int grid = (num_tokens < GRID) ? num_tokens : GRID;
    moe_scatter_kernel<<<grid, THREADS, 0, stream>>>(
        token_hidden, expert_idx, slot_idx, expert_offsets, out, num_tokens);
}